// Round 2
// baseline (282.042 us; speedup 1.0000x reference)
//
#include <hip/hip_runtime.h>
#include <hip/hip_bf16.h>

// Problem dims (fixed by the reference)
#define NTOK   (256 * 512)     // B*S tokens
#define HD     512
#define INTD   256
#define N_TEST 1500
#define N_USER 7442

static __device__ __forceinline__ float4 ld4(const float* p) {
    return *reinterpret_cast<const float4*>(p);
}

// P[i][:] = E[i][:] @ W  (W is [K][256] row-major), R rows, K = 256 or 512.
// Block: 256 threads, 8 rows per block staged in LDS; thread j owns column j.
template <int K>
__global__ __launch_bounds__(256) void proj_kernel(const float* __restrict__ E,
                                                   const float* __restrict__ W,
                                                   float* __restrict__ P,
                                                   int R) {
    __shared__ float lds[8 * K];
    const int tid  = threadIdx.x;
    const int row0 = blockIdx.x * 8;

    #pragma unroll
    for (int r = 0; r < 8; ++r) {
        const int row = row0 + r;
        if (row < R) {
            for (int m = tid; m < K; m += 256)
                lds[r * K + m] = E[(size_t)row * K + m];
        }
    }
    __syncthreads();

    float acc[8] = {0.f, 0.f, 0.f, 0.f, 0.f, 0.f, 0.f, 0.f};
    #pragma unroll 4
    for (int m = 0; m < K; ++m) {
        const float w = W[m * 256 + tid];   // coalesced; LDS reads below broadcast
        #pragma unroll
        for (int r = 0; r < 8; ++r)
            acc[r] += lds[r * K + m] * w;
    }

    #pragma unroll
    for (int r = 0; r < 8; ++r) {
        const int row = row0 + r;
        if (row < R) P[(size_t)row * 256 + tid] = acc[r];
    }
}

// biasC[j] = comb_b[j] + sum_m graph_b[m] * W4[m][j]
__global__ __launch_bounds__(256) void bias_kernel(const float* __restrict__ comb_b,
                                                   const float* __restrict__ graph_b,
                                                   const float* __restrict__ W4,
                                                   float* __restrict__ biasC) {
    const int j = threadIdx.x;
    float acc = comb_b[j];
    for (int m = 0; m < 256; ++m) acc += graph_b[m] * W4[m * 256 + j];
    biasC[j] = acc;
}

// One wave (64 lanes) per token; lane owns 4 columns. 4 tokens per 256-thread block.
__global__ __launch_bounds__(256) void main_kernel(
    const int* __restrict__ testId, const int* __restrict__ itemId,
    const int* __restrict__ tagId,  const int* __restrict__ inter,
    const float* __restrict__ cont_feats,
    const float* __restrict__ Pint, const float* __restrict__ Ptest,
    const float* __restrict__ Pitem, const float* __restrict__ Ptag,
    const float* __restrict__ Pg,   const float* __restrict__ biasC,
    const float* __restrict__ comb_g, const float* __restrict__ comb_beta,
    const float* __restrict__ cont_W, const float* __restrict__ cont_b,
    const float* __restrict__ cont_g, const float* __restrict__ cont_beta,
    float* __restrict__ out) {
    const int wave = threadIdx.x >> 6;
    const int lane = threadIdx.x & 63;
    const int t    = blockIdx.x * 4 + wave;   // grid sized exactly: always < NTOK

    const int ti = testId[t];
    const int ii = itemId[t];
    const int tg = tagId[t];
    const int iv = inter[t];
    const int c  = lane * 4;                  // column base, 16B aligned

    // ---- cate path: sum of 5 projected rows + fused bias ----
    float4 a0 = ld4(Pint  + iv * 256 + c);
    float4 a1 = ld4(Ptest + ti * 256 + c);
    float4 a2 = ld4(Pitem + ii * 256 + c);
    float4 a3 = ld4(Ptag  + tg * 256 + c);
    float4 a4 = ld4(Pg    + ti * 256 + c);
    float4 ab = ld4(biasC + c);
    float vx = a0.x + a1.x + a2.x + a3.x + a4.x + ab.x;
    float vy = a0.y + a1.y + a2.y + a3.y + a4.y + ab.y;
    float vz = a0.z + a1.z + a2.z + a3.z + a4.z + ab.z;
    float vw = a0.w + a1.w + a2.w + a3.w + a4.w + ab.w;

    float s  = vx + vy + vz + vw;
    float ss = vx * vx + vy * vy + vz * vz + vw * vw;
    #pragma unroll
    for (int off = 32; off >= 1; off >>= 1) {
        s  += __shfl_xor(s,  off, 64);
        ss += __shfl_xor(ss, off, 64);
    }
    float mu  = s * (1.f / 256.f);
    float var = ss * (1.f / 256.f) - mu * mu;
    float inv = rsqrtf(var + 1e-5f);

    float4 g4 = ld4(comb_g + c);
    float4 b4 = ld4(comb_beta + c);
    float4 o1;
    o1.x = (vx - mu) * inv * g4.x + b4.x;
    o1.y = (vy - mu) * inv * g4.y + b4.y;
    o1.z = (vz - mu) * inv * g4.z + b4.z;
    o1.w = (vw - mu) * inv * g4.w + b4.w;
    *reinterpret_cast<float4*>(out + (size_t)t * 512 + c) = o1;

    // ---- cont path: [3] @ cont_W[3][256] + LN ----
    const float c0 = cont_feats[t * 3 + 0];
    const float c1 = cont_feats[t * 3 + 1];
    const float c2 = cont_feats[t * 3 + 2];
    float4 w0 = ld4(cont_W + 0 * 256 + c);
    float4 w1 = ld4(cont_W + 1 * 256 + c);
    float4 w2 = ld4(cont_W + 2 * 256 + c);
    float4 cb = ld4(cont_b + c);
    float ux = c0 * w0.x + c1 * w1.x + c2 * w2.x + cb.x;
    float uy = c0 * w0.y + c1 * w1.y + c2 * w2.y + cb.y;
    float uz = c0 * w0.z + c1 * w1.z + c2 * w2.z + cb.z;
    float uw = c0 * w0.w + c1 * w1.w + c2 * w2.w + cb.w;

    float s2  = ux + uy + uz + uw;
    float ss2 = ux * ux + uy * uy + uz * uz + uw * uw;
    #pragma unroll
    for (int off = 32; off >= 1; off >>= 1) {
        s2  += __shfl_xor(s2,  off, 64);
        ss2 += __shfl_xor(ss2, off, 64);
    }
    float mu2  = s2 * (1.f / 256.f);
    float var2 = ss2 * (1.f / 256.f) - mu2 * mu2;
    float inv2 = rsqrtf(var2 + 1e-5f);

    float4 g42 = ld4(cont_g + c);
    float4 b42 = ld4(cont_beta + c);
    float4 o2;
    o2.x = (ux - mu2) * inv2 * g42.x + b42.x;
    o2.y = (uy - mu2) * inv2 * g42.y + b42.y;
    o2.z = (uz - mu2) * inv2 * g42.z + b42.z;
    o2.w = (uw - mu2) * inv2 * g42.w + b42.w;
    *reinterpret_cast<float4*>(out + (size_t)t * 512 + 256 + c) = o2;
}

extern "C" void kernel_launch(void* const* d_in, const int* in_sizes, int n_in,
                              void* d_out, int out_size, void* d_ws, size_t ws_size,
                              hipStream_t stream) {
    const int*   testId     = (const int*)d_in[0];
    const int*   itemId     = (const int*)d_in[1];
    const int*   tagId      = (const int*)d_in[2];
    const float* cont_feats = (const float*)d_in[3];
    const int*   inter      = (const int*)d_in[4];
    const float* emb_int    = (const float*)d_in[5];
    const float* emb_test   = (const float*)d_in[6];
    const float* emb_item   = (const float*)d_in[7];
    const float* emb_tag    = (const float*)d_in[8];
    const float* graph_tab  = (const float*)d_in[9];
    const float* graph_W    = (const float*)d_in[10];
    const float* graph_b    = (const float*)d_in[11];
    const float* comb_W     = (const float*)d_in[12];
    const float* comb_b     = (const float*)d_in[13];
    const float* comb_g     = (const float*)d_in[14];
    const float* comb_beta  = (const float*)d_in[15];
    const float* cont_W     = (const float*)d_in[16];
    const float* cont_b     = (const float*)d_in[17];
    const float* cont_g     = (const float*)d_in[18];
    const float* cont_beta  = (const float*)d_in[19];
    float* out              = (float*)d_out;   // reference output dtype is float32

    // Workspace layout (floats). Total = 3,554,560 f32 = 14.2 MB.
    float* ws    = (float*)d_ws;
    float* GW4   = ws;                       // 512*256
    float* Pint  = GW4   + 512 * 256;        // 3*256
    float* Ptest = Pint  + 3 * 256;          // 1501*256
    float* Pitem = Ptest + 1501 * 256;       // 9455*256
    float* Ptag  = Pitem + 9455 * 256;       // 913*256
    float* Pg    = Ptag  + 913 * 256;        // 1500*256
    float* biasC = Pg    + 1500 * 256;       // 256

    // comb_W chunks: concat order [e_int, e_test, e_item, e_tag, g]
    const float* W0 = comb_W;                // interaction
    const float* W1 = comb_W + 256 * 256;    // testId
    const float* W2 = comb_W + 512 * 256;    // itemId
    const float* W3 = comb_W + 768 * 256;    // tag
    const float* W4 = comb_W + 1024 * 256;   // graph

    // Precompute: fold matmuls through the (tiny) embedding tables.
    proj_kernel<256><<<(512  + 7) / 8, 256, 0, stream>>>(graph_W,  W4,  GW4,   512);
    proj_kernel<256><<<1,              256, 0, stream>>>(emb_int,  W0,  Pint,  3);
    proj_kernel<256><<<(1501 + 7) / 8, 256, 0, stream>>>(emb_test, W1,  Ptest, 1501);
    proj_kernel<256><<<(9455 + 7) / 8, 256, 0, stream>>>(emb_item, W2,  Pitem, 9455);
    proj_kernel<256><<<(913  + 7) / 8, 256, 0, stream>>>(emb_tag,  W3,  Ptag,  913);
    proj_kernel<512><<<(1500 + 7) / 8, 256, 0, stream>>>(
        graph_tab + (size_t)(N_USER - 1) * HD, GW4, Pg, N_TEST);
    bias_kernel<<<1, 256, 0, stream>>>(comb_b, graph_b, W4, biasC);

    // Main: 4 tokens per block (one wave each).
    main_kernel<<<NTOK / 4, 256, 0, stream>>>(
        testId, itemId, tagId, inter, cont_feats,
        Pint, Ptest, Pitem, Ptag, Pg, biasC,
        comb_g, comb_beta, cont_W, cont_b, cont_g, cont_beta, out);
}

// Round 4
// 164.788 us; speedup vs baseline: 1.7115x; 1.7115x over previous
//
#include <hip/hip_runtime.h>
#include <hip/hip_bf16.h>

// Problem dims (fixed by the reference)
#define NTOK   (256 * 512)     // B*S tokens
#define N_USER 7442

using bf16 = __hip_bfloat16;
typedef float f32x4 __attribute__((ext_vector_type(4)));  // native vec for nontemporal builtin

static __device__ __forceinline__ float4 ld4(const float* p) {
    return *reinterpret_cast<const float4*>(p);
}
// bf16 pair unpack (little-endian: element at lower address = low 16 bits)
static __device__ __forceinline__ float bfl(unsigned u) {
    union { unsigned u; float f; } c; c.u = u << 16; return c.f;
}
static __device__ __forceinline__ float bfh(unsigned u) {
    union { unsigned u; float f; } c; c.u = u & 0xFFFF0000u; return c.f;
}
static __device__ __forceinline__ void st_nt4(float* p, float x, float y, float z, float w) {
    f32x4 v; v.x = x; v.y = y; v.z = z; v.w = w;
    __builtin_nontemporal_store(v, reinterpret_cast<f32x4*>(p));
}

// ---- precompute geometry ----
#define RS 32                 // rows/block, simple path (K=256)
#define RG 16                 // rows/block, graph-fused path
#define NB_ITEM  296          // ceil(9455/32)
#define NB_TAG   29           // ceil(913/32)
#define NB_INT   1            // 3 rows
#define NB_TESTG 94           // ceil(1500/16)
#define NB_TOTAL (NB_ITEM + NB_TAG + NB_INT + NB_TESTG)

// One kernel computes all folded tables:
//   Pitem  = emb_item @ W2                       (bf16, 9455x256)
//   Ptag   = emb_tag  @ W3                       (bf16,  913x256)
//   Pint   = emb_int  @ W0                       (bf16,    3x256)
//   Ptestg = emb_test @ W1 + (graph_rows @ graph_W) @ W4 + comb_b + graph_b @ W4
__global__ __launch_bounds__(256) void precompute_kernel(
    const float* __restrict__ emb_int,  const float* __restrict__ emb_test,
    const float* __restrict__ emb_item, const float* __restrict__ emb_tag,
    const float* __restrict__ graph_tab, const float* __restrict__ graph_W,
    const float* __restrict__ graph_b,
    const float* __restrict__ comb_W,   const float* __restrict__ comb_b,
    bf16* __restrict__ Pint, bf16* __restrict__ Ptestg,
    bf16* __restrict__ Pitem, bf16* __restrict__ Ptag) {
    __shared__ float lds[12288];  // 48 KB
    const int tid = threadIdx.x;
    const int b   = blockIdx.x;

    const float* W0 = comb_W;              // interaction
    const float* W1 = comb_W + 256 * 256;  // testId
    const float* W2 = comb_W + 512 * 256;  // itemId
    const float* W3 = comb_W + 768 * 256;  // tag
    const float* W4 = comb_W + 1024 * 256; // graph

    if (b < NB_ITEM + NB_TAG + NB_INT) {
        // -------- simple path: P = E @ W, K = 256 --------
        const float* E; const float* W; bf16* P; int row0, R;
        if (b < NB_ITEM)               { E = emb_item; W = W2; P = Pitem; row0 = b * RS;              R = 9455; }
        else if (b < NB_ITEM + NB_TAG) { E = emb_tag;  W = W3; P = Ptag;  row0 = (b - NB_ITEM) * RS;  R = 913;  }
        else                           { E = emb_int;  W = W0; P = Pint;  row0 = 0;                   R = 3;    }
        const int nr = min(RS, R - row0);

        for (int i = tid; i < nr * 256; i += 256) {
            const int r = i >> 8, m = i & 255;
            lds[r * 256 + m] = E[(size_t)(row0 + r) * 256 + m];
        }
        __syncthreads();

        float acc[RS];
        #pragma unroll
        for (int r = 0; r < RS; ++r) acc[r] = 0.f;
        for (int m = 0; m < 256; m += 4) {
            const float w0 = W[(m + 0) * 256 + tid];
            const float w1 = W[(m + 1) * 256 + tid];
            const float w2 = W[(m + 2) * 256 + tid];
            const float w3 = W[(m + 3) * 256 + tid];
            #pragma unroll
            for (int r = 0; r < RS; ++r) {
                const float4 e = ld4(&lds[r * 256 + m]);
                acc[r] += e.x * w0 + e.y * w1 + e.z * w2 + e.w * w3;
            }
        }
        for (int r = 0; r < nr; ++r)
            P[(size_t)(row0 + r) * 256 + tid] = __float2bfloat16(acc[r]);
    } else {
        // -------- graph+test fused path --------
        const int gb   = b - (NB_ITEM + NB_TAG + NB_INT);
        const int row0 = gb * RG;
        const int nr   = min(RG, 1500 - row0);
        float* ldsG = lds;          // 16x512 (phase A/B), then 16x256 emb_test (phase C)
        float* ldsT = lds + 8192;   // 16x256 tmp

        // A: stage graph rows
        for (int i = tid; i < nr * 512; i += 256) {
            const int r = i >> 9, m = i & 511;
            ldsG[r * 512 + m] = graph_tab[(size_t)(N_USER - 1 + row0 + r) * 512 + m];
        }
        __syncthreads();

        // B: tmp = rows @ graph_W   (K = 512)
        float acc[RG];
        #pragma unroll
        for (int r = 0; r < RG; ++r) acc[r] = 0.f;
        for (int m = 0; m < 512; m += 4) {
            const float w0 = graph_W[(m + 0) * 256 + tid];
            const float w1 = graph_W[(m + 1) * 256 + tid];
            const float w2 = graph_W[(m + 2) * 256 + tid];
            const float w3 = graph_W[(m + 3) * 256 + tid];
            #pragma unroll
            for (int r = 0; r < RG; ++r) {
                const float4 e = ld4(&ldsG[r * 512 + m]);
                acc[r] += e.x * w0 + e.y * w1 + e.z * w2 + e.w * w3;
            }
        }
        __syncthreads();   // all reads of ldsG done before overwrite; ldsT writes below

        for (int r = 0; r < nr; ++r) ldsT[r * 256 + tid] = acc[r];
        for (int i = tid; i < nr * 256; i += 256) {
            const int r = i >> 8, m = i & 255;
            ldsG[r * 256 + m] = emb_test[(size_t)(row0 + r) * 256 + m];
        }
        __syncthreads();

        // C: P = tmp @ W4 + test @ W1 (+ graph_b @ W4 + comb_b)
        float acc2[RG];
        float bacc = 0.f;
        #pragma unroll
        for (int r = 0; r < RG; ++r) acc2[r] = 0.f;
        for (int m = 0; m < 256; m += 4) {
            const float w40 = W4[(m + 0) * 256 + tid];
            const float w41 = W4[(m + 1) * 256 + tid];
            const float w42 = W4[(m + 2) * 256 + tid];
            const float w43 = W4[(m + 3) * 256 + tid];
            const float w10 = W1[(m + 0) * 256 + tid];
            const float w11 = W1[(m + 1) * 256 + tid];
            const float w12 = W1[(m + 2) * 256 + tid];
            const float w13 = W1[(m + 3) * 256 + tid];
            bacc += graph_b[m + 0] * w40 + graph_b[m + 1] * w41 +
                    graph_b[m + 2] * w42 + graph_b[m + 3] * w43;
            #pragma unroll
            for (int r = 0; r < RG; ++r) {
                const float4 tv = ld4(&ldsT[r * 256 + m]);
                const float4 ev = ld4(&ldsG[r * 256 + m]);
                acc2[r] += tv.x * w40 + tv.y * w41 + tv.z * w42 + tv.w * w43 +
                           ev.x * w10 + ev.y * w11 + ev.z * w12 + ev.w * w13;
            }
        }
        const float bias = bacc + comb_b[tid];
        for (int r = 0; r < nr; ++r)
            Ptestg[(size_t)(row0 + r) * 256 + tid] = __float2bfloat16(acc2[r] + bias);
    }
}

// One wave per token; lane owns 4 columns. 4 tokens per 256-thread block.
__global__ __launch_bounds__(256) void main_kernel(
    const int* __restrict__ testId, const int* __restrict__ itemId,
    const int* __restrict__ tagId,  const int* __restrict__ inter,
    const float* __restrict__ cont_feats,
    const bf16* __restrict__ Pint, const bf16* __restrict__ Ptestg,
    const bf16* __restrict__ Pitem, const bf16* __restrict__ Ptag,
    const float* __restrict__ comb_g, const float* __restrict__ comb_beta,
    const float* __restrict__ cont_W, const float* __restrict__ cont_b,
    const float* __restrict__ cont_g, const float* __restrict__ cont_beta,
    float* __restrict__ out) {
    const int wave = threadIdx.x >> 6;
    const int lane = threadIdx.x & 63;
    const int t    = blockIdx.x * 4 + wave;

    const int ti = testId[t];
    const int ii = itemId[t];
    const int tg = tagId[t];
    const int iv = inter[t];
    const int c  = lane * 4;

    // ---- cate path: 4 bf16 gathers (Ptestg carries bias) ----
    const uint2 u0 = *reinterpret_cast<const uint2*>(Pint   + iv * 256 + c);
    const uint2 u1 = *reinterpret_cast<const uint2*>(Ptestg + (size_t)ti * 256 + c);
    const uint2 u2 = *reinterpret_cast<const uint2*>(Pitem  + (size_t)ii * 256 + c);
    const uint2 u3 = *reinterpret_cast<const uint2*>(Ptag   + (size_t)tg * 256 + c);
    float vx = bfl(u0.x) + bfl(u1.x) + bfl(u2.x) + bfl(u3.x);
    float vy = bfh(u0.x) + bfh(u1.x) + bfh(u2.x) + bfh(u3.x);
    float vz = bfl(u0.y) + bfl(u1.y) + bfl(u2.y) + bfl(u3.y);
    float vw = bfh(u0.y) + bfh(u1.y) + bfh(u2.y) + bfh(u3.y);

    float s  = vx + vy + vz + vw;
    float ss = vx * vx + vy * vy + vz * vz + vw * vw;
    #pragma unroll
    for (int off = 32; off >= 1; off >>= 1) {
        s  += __shfl_xor(s,  off, 64);
        ss += __shfl_xor(ss, off, 64);
    }
    const float mu  = s * (1.f / 256.f);
    const float var = ss * (1.f / 256.f) - mu * mu;
    const float inv = rsqrtf(var + 1e-5f);

    const float4 g4 = ld4(comb_g + c);
    const float4 b4 = ld4(comb_beta + c);
    st_nt4(out + (size_t)t * 512 + c,
           (vx - mu) * inv * g4.x + b4.x,
           (vy - mu) * inv * g4.y + b4.y,
           (vz - mu) * inv * g4.z + b4.z,
           (vw - mu) * inv * g4.w + b4.w);

    // ---- cont path: [3] @ cont_W[3][256] + LN ----
    const float c0 = cont_feats[t * 3 + 0];
    const float c1 = cont_feats[t * 3 + 1];
    const float c2 = cont_feats[t * 3 + 2];
    const float4 w0 = ld4(cont_W + 0 * 256 + c);
    const float4 w1 = ld4(cont_W + 1 * 256 + c);
    const float4 w2 = ld4(cont_W + 2 * 256 + c);
    const float4 cb = ld4(cont_b + c);
    float ux = c0 * w0.x + c1 * w1.x + c2 * w2.x + cb.x;
    float uy = c0 * w0.y + c1 * w1.y + c2 * w2.y + cb.y;
    float uz = c0 * w0.z + c1 * w1.z + c2 * w2.z + cb.z;
    float uw = c0 * w0.w + c1 * w1.w + c2 * w2.w + cb.w;

    float s2  = ux + uy + uz + uw;
    float ss2 = ux * ux + uy * uy + uz * uz + uw * uw;
    #pragma unroll
    for (int off = 32; off >= 1; off >>= 1) {
        s2  += __shfl_xor(s2,  off, 64);
        ss2 += __shfl_xor(ss2, off, 64);
    }
    const float mu2  = s2 * (1.f / 256.f);
    const float var2 = ss2 * (1.f / 256.f) - mu2 * mu2;
    const float inv2 = rsqrtf(var2 + 1e-5f);

    const float4 g42 = ld4(cont_g + c);
    const float4 b42 = ld4(cont_beta + c);
    st_nt4(out + (size_t)t * 512 + 256 + c,
           (ux - mu2) * inv2 * g42.x + b42.x,
           (uy - mu2) * inv2 * g42.y + b42.y,
           (uz - mu2) * inv2 * g42.z + b42.z,
           (uw - mu2) * inv2 * g42.w + b42.w);
}

extern "C" void kernel_launch(void* const* d_in, const int* in_sizes, int n_in,
                              void* d_out, int out_size, void* d_ws, size_t ws_size,
                              hipStream_t stream) {
    const int*   testId     = (const int*)d_in[0];
    const int*   itemId     = (const int*)d_in[1];
    const int*   tagId      = (const int*)d_in[2];
    const float* cont_feats = (const float*)d_in[3];
    const int*   inter      = (const int*)d_in[4];
    const float* emb_int    = (const float*)d_in[5];
    const float* emb_test   = (const float*)d_in[6];
    const float* emb_item   = (const float*)d_in[7];
    const float* emb_tag    = (const float*)d_in[8];
    const float* graph_tab  = (const float*)d_in[9];
    const float* graph_W    = (const float*)d_in[10];
    const float* graph_b    = (const float*)d_in[11];
    const float* comb_W     = (const float*)d_in[12];
    const float* comb_b     = (const float*)d_in[13];
    const float* comb_g     = (const float*)d_in[14];
    const float* comb_beta  = (const float*)d_in[15];
    const float* cont_W     = (const float*)d_in[16];
    const float* cont_b     = (const float*)d_in[17];
    const float* cont_g     = (const float*)d_in[18];
    const float* cont_beta  = (const float*)d_in[19];
    float* out              = (float*)d_out;

    // Workspace: bf16 tables, each offset 256-element aligned. ~6.1 MB total.
    bf16* ws     = (bf16*)d_ws;
    bf16* Pitem  = ws;                         // 9455*256
    bf16* Ptestg = Pitem  + 9455 * 256;        // 1500*256 (test + graph + bias fused)
    bf16* Ptag   = Ptestg + 1500 * 256;        //  913*256
    bf16* Pint   = Ptag   +  913 * 256;        //    3*256

    precompute_kernel<<<NB_TOTAL, 256, 0, stream>>>(
        emb_int, emb_test, emb_item, emb_tag, graph_tab, graph_W, graph_b,
        comb_W, comb_b, Pint, Ptestg, Pitem, Ptag);

    main_kernel<<<NTOK / 4, 256, 0, stream>>>(
        testId, itemId, tagId, inter, cont_feats,
        Pint, Ptestg, Pitem, Ptag,
        comb_g, comb_beta, cont_W, cont_b, cont_g, cont_beta, out);
}